// Round 6
// baseline (520.445 us; speedup 1.0000x reference)
//
#include <hip/hip_runtime.h>
#include <stdint.h>

typedef _Float16 f16;
typedef _Float16 f16x8 __attribute__((ext_vector_type(8)));
typedef _Float16 f16x4 __attribute__((ext_vector_type(4)));
typedef float f32x4 __attribute__((ext_vector_type(4)));

#define GAS __attribute__((address_space(1)))
#define LAS __attribute__((address_space(3)))

// async global->LDS, 16 B per lane; LDS dest = wave-uniform base + lane*16
__device__ __forceinline__ void gl_lds16(const void* g, void* l) {
    __builtin_amdgcn_global_load_lds((const GAS uint32_t*)g, (LAS uint32_t*)l, 16, 0, 0);
}

__global__ __launch_bounds__(256) void zerof(float* __restrict__ p, int n) {
    int i = blockIdx.x * 256 + threadIdx.x;
    if (i < n) p[i] = 0.f;
}

__global__ __launch_bounds__(256) void cvt16(const float* __restrict__ in,
                                             f16* __restrict__ o, long n) {
    long i = (long)blockIdx.x * 256 + threadIdx.x;
    if (i < n) o[i] = (f16)in[i];
}

// w [27][Cin][Cout] fp32 -> wt [27][Cout][Cin] fp16 (B-fragment: 16B contiguous Cin)
__global__ __launch_bounds__(256) void wtrans16(const float* __restrict__ w,
                                                f16* __restrict__ wt,
                                                int Cin, int Cout) {
    long i = (long)blockIdx.x * 256 + threadIdx.x;
    long total = 27L * Cin * Cout;
    if (i >= total) return;
    int ci = (int)(i % Cin);
    long t = i / Cin;
    int co = (int)(t % Cout);
    int k  = (int)(t / Cout);
    wt[i] = (f16)w[((long)k * Cin + ci) * Cout + co];
}

// Dense implicit 3x3x3 conv, occupancy-first:
//  Block tile: 64 rows (4y x 16x) x 64 cols (col-half split across blocks for
//  COUT=128). LDS: A halo slab 6y x 18x x 128ch = 27648 B (single-buffer per
//  z-stage) + B tap panel [64][128ch] dbuf 2x16 KB = 60416 B -> 2 blocks/CU
//  (8 waves = 2/SIMD). Layer 2: B 2x8 KB -> 44032 B -> 3 blocks/CU.
//  Waves (mid): 2x2 of 32rows x 32cols (RT=2,CT=2, acc=16 VGPR).
//  Per tap: [issue B(t+1) DMA] [compute t from LDS] [sync]; stalls covered by
//  the co-resident sibling block(s).
// LAYER 0: CIN=256 (2 ch-halves, 1 in-plane, dz=1-p), COUT=128, grid 3*144*2
// LAYER 1: CIN=128, 3 in-planes, j=p+dz,   COUT=128, grid 3*144*2
// LAYER 2: CIN=128, 3 in-planes, j=p+dz-1, COUT=32,  grid 5*144
template <int LAYER>
__global__ __launch_bounds__(256) void conv_dense(
    const f16* __restrict__ fin, const f16* __restrict__ wt,
    const f16* __restrict__ zrow, float* __restrict__ out,
    float* __restrict__ stats) {
    constexpr int COUT = (LAYER == 2) ? 32 : 128;
    constexpr int CS   = (LAYER == 2) ? 1 : 2;       // col-split factor
    constexpr int BCOL = COUT / CS;                  // cols per block (64/32)
    constexpr int INRB = (LAYER == 0) ? 512 : 256;   // input row bytes
    constexpr int WRB  = (LAYER == 0) ? 512 : 256;   // weight row bytes per col
    constexpr int RT   = (LAYER == 2) ? 1 : 2;       // 16-row tiles per wave
    constexpr int CT   = 2;                          // 16-col tiles per wave
    constexpr int NBCH = BCOL / 4;                   // B chunks (1 KB each)
    extern __shared__ char smem[];
    char* ldsA  = smem;                              // 27648
    char* ldsB0 = smem + 27648;                      // BCOL*256
    char* ldsB1 = smem + 27648 + BCOL * 256;

    const int b = blockIdx.x;
    int p, t0, chh;
    if (CS == 2) { p = b / 288; int r = b % 288; t0 = r >> 1; chh = r & 1; }
    else         { p = b / 144; t0 = b % 144; chh = 0; }
    const int y0 = (t0 / 6) * 4;
    const int x0 = (t0 % 6) * 16;
    const int cbase = chh * 64;
    const int tid = threadIdx.x;
    const int lane = tid & 63;
    const int wave = tid >> 6;
    const int q = lane >> 4;
    const int r16 = lane & 15;
    const int wry = (LAYER == 2) ? wave : (wave >> 1) * 2;   // y-row base in tile
    const int wcl = (LAYER == 2) ? 0 : (wave & 1) * 32;      // local col base

    // stage list (block-uniform): z-planes (ch-halves for LAYER 0)
    int S = 0;
    int js[3], dzs[3], hs[3];
    if (LAYER == 0) {
        js[0] = 0; dzs[0] = 1 - p; hs[0] = 0;
        js[1] = 0; dzs[1] = 1 - p; hs[1] = 1;
        S = 2;
    } else if (LAYER == 1) {
        for (int dz = -1; dz <= 1; dz++) {
            int j = p + dz;
            if (0 <= j && j < 3) { js[S] = j; dzs[S] = dz; hs[S] = 0; S++; }
        }
    } else {
        for (int dz = -1; dz <= 1; dz++) {
            int j = p + dz - 1;
            if (0 <= j && j < 3) { js[S] = j; dzs[S] = dz; hs[S] = 0; S++; }
        }
    }

    auto stageA = [&](int s) {
        const int j = js[s], h = hs[s];
        const long pbase = (long)j * 9216;
        for (int ch = wave; ch < 27; ch += 4) {
            int site = ch * 4 + q;
            int sy = site / 18;
            int sx = site - sy * 18;
            int y = y0 - 1 + sy;
            int x = x0 - 1 + sx;
            int cc = r16 ^ (site & 7);
            bool ok = ((unsigned)y < 96u) & ((unsigned)x < 96u);
            const char* src = ok
                ? (const char*)fin + (pbase + y * 96 + x) * INRB + h * 256 + cc * 16
                : (const char*)zrow + cc * 16;
            gl_lds16(src, ldsA + ch * 1024);
        }
    };
    auto stageB = [&](int k, int h, char* buf) {
        for (int ch = wave; ch < NBCH; ch += 4) {
            int col = ch * 4 + q;                  // local col
            int cc = r16 ^ (col & 7);
            const char* src = (const char*)wt + (long)(k * COUT + cbase + col) * WRB +
                              h * 256 + cc * 16;
            gl_lds16(src, buf + ch * 1024);
        }
    };

    f32x4 acc[RT][CT];
#pragma unroll
    for (int tr = 0; tr < RT; tr++)
#pragma unroll
        for (int c = 0; c < CT; c++) acc[tr][c] = f32x4{0.f, 0.f, 0.f, 0.f};

    stageA(0);
    stageB((dzs[0] + 1) * 9, hs[0], ldsB0);

    int tap = 0;
    const int NT = S * 9;
    for (int s = 0; s < S; s++) {
        if (s > 0) stageA(s);       // slab free: all waves passed last tap's sync
        __syncthreads();            // drain A(s) (+ pending B)
#pragma unroll 1
        for (int i = 0; i < 9; i++, tap++) {
            if (tap + 1 < NT) {
                int sn = (i == 8) ? s + 1 : s;
                int in2 = (i == 8) ? 0 : i + 1;
                stageB((dzs[sn] + 1) * 9 + in2, hs[sn], ((tap + 1) & 1) ? ldsB1 : ldsB0);
            }
            const char* bufB = (tap & 1) ? ldsB1 : ldsB0;
            const int dy = i / 3 - 1, dx = i % 3 - 1;
#pragma unroll
            for (int kk = 0; kk < 4; kk++) {
                const int c16 = kk * 4 + q;
                f16x8 Af[RT], Bf[CT];
#pragma unroll
                for (int tr = 0; tr < RT; tr++) {
                    int site = (wry + tr + 1 + dy) * 18 + 1 + dx + r16;
                    Af[tr] = *(const f16x8*)(ldsA + site * 256 +
                                             ((c16 ^ (site & 7)) << 4));
                }
#pragma unroll
                for (int c = 0; c < CT; c++) {
                    int col = wcl + c * 16 + r16;
                    Bf[c] = *(const f16x8*)(bufB + col * 256 +
                                            ((c16 ^ (col & 7)) << 4));
                }
#pragma unroll
                for (int tr = 0; tr < RT; tr++)
#pragma unroll
                    for (int c = 0; c < CT; c++)
                        acc[tr][c] = __builtin_amdgcn_mfma_f32_16x16x32_f16(
                            Af[tr], Bf[c], acc[tr][c], 0, 0, 0);
            }
            __syncthreads();        // drain B(tap+1); publish/protect buffers
        }
    }
    // Epilogue: D row = q*4+reg within a 16-site (x) tile; write + fused BN stats.
#pragma unroll
    for (int c = 0; c < CT; c++) {
        const int col = cbase + wcl + c * 16 + r16;
        float sum = 0.f, ssq = 0.f;
#pragma unroll
        for (int tr = 0; tr < RT; tr++) {
            const int ly = wry + tr;
#pragma unroll
            for (int r = 0; r < 4; r++) {
                const int lx = q * 4 + r;
                float v = acc[tr][c][r];
                out[((long)p * 9216 + (long)(y0 + ly) * 96 + x0 + lx) * COUT + col] = v;
                sum += v;
                ssq = fmaf(v, v, ssq);
            }
        }
        sum += __shfl_xor(sum, 16);
        sum += __shfl_xor(sum, 32);
        ssq += __shfl_xor(ssq, 16);
        ssq += __shfl_xor(ssq, 32);
        if (q == 0) {
            atomicAdd(&stats[col], sum);
            atomicAdd(&stats[COUT + col], ssq);
        }
    }
}

// BN(train) + optional residual + ReLU, 4 elems/thread.
__global__ __launch_bounds__(256) void bn_apply4(
    const float4* __restrict__ f, const float* __restrict__ sums,
    const float* __restrict__ g, const float* __restrict__ bta,
    const f16x4* __restrict__ idn, f16* __restrict__ outh,
    float4* __restrict__ outf, long n4, int C, float invM) {
    long i = (long)blockIdx.x * 256 + threadIdx.x;
    if (i >= n4) return;
    int col0 = (int)((i * 4) & (C - 1));
    float4 v = f[i];
    float r[4] = {v.x, v.y, v.z, v.w};
    f16x4 id = {};
    if (idn) id = idn[i];
    f16x4 ho;
#pragma unroll
    for (int j = 0; j < 4; j++) {
        int c = col0 + j;
        float mu = sums[c] * invM;
        float var = sums[C + c] * invM - mu * mu;
        var = fmaxf(var, 0.f);
        float sc = g[c] * rsqrtf(var + 1e-5f);
        float x = (r[j] - mu) * sc + bta[c];
        if (idn) x += (float)id[j];
        x = fmaxf(x, 0.f);
        r[j] = x;
        ho[j] = (f16)x;
    }
    if (outf) outf[i] = make_float4(r[0], r[1], r[2], r[3]);
    else *(f16x4*)(outh + i * 4) = ho;
}

extern "C" void kernel_launch(void* const* d_in, const int* in_sizes, int n_in,
                              void* d_out, int out_size, void* d_ws, size_t ws_size,
                              hipStream_t stream) {
    (void)n_in; (void)out_size; (void)ws_size;
    const float* x    = (const float*)d_in[0];
    const float* w_s1 = (const float*)d_in[1];
    const float* g_s1 = (const float*)d_in[2];
    const float* b_s1 = (const float*)d_in[3];
    const float* w11  = (const float*)d_in[4];
    const float* g11  = (const float*)d_in[5];
    const float* b11  = (const float*)d_in[6];
    const float* w12  = (const float*)d_in[7];
    const float* g12  = (const float*)d_in[8];
    const float* b12  = (const float*)d_in[9];
    const float* w21  = (const float*)d_in[10];
    const float* g21  = (const float*)d_in[11];
    const float* b21  = (const float*)d_in[12];
    const float* w22  = (const float*)d_in[13];
    const float* g22  = (const float*)d_in[14];
    const float* b22  = (const float*)d_in[15];
    const float* w_s2 = (const float*)d_in[16];
    const float* g_s2 = (const float*)d_in[17];
    const float* b_s2 = (const float*)d_in[18];

    const int N0 = in_sizes[0] / 256;   // 9216
    const int M1 = in_sizes[19] / 27;   // 27648
    const int M2 = in_sizes[21] / 27;   // 46080

    char* base = (char*)d_ws;
    size_t off = 0;
    auto alloc = [&](size_t bytes) -> char* {
        off = (off + 255) & ~(size_t)255;
        char* p = base + off;
        off += bytes;
        return p;
    };
    f16* xh  = (f16*)alloc((size_t)N0 * 256 * 2);
    f16* w1  = (f16*)alloc(27UL * 128 * 256 * 2);
    f16* wa1 = (f16*)alloc(27UL * 128 * 128 * 2);
    f16* wa2 = (f16*)alloc(27UL * 128 * 128 * 2);
    f16* wb1 = (f16*)alloc(27UL * 128 * 128 * 2);
    f16* wb2 = (f16*)alloc(27UL * 128 * 128 * 2);
    f16* w2  = (f16*)alloc(27UL * 32 * 128 * 2);
    f16* fA  = (f16*)alloc((size_t)M1 * 128 * 2);
    f16* fB  = (f16*)alloc((size_t)M1 * 128 * 2);
    float* cbuf  = (float*)alloc((size_t)M1 * 128 * 4);  // covers M2*32 too
    float* stats = (float*)alloc(1344UL * 4);            // 5x256 + 64
    f16*   zrow  = (f16*)alloc(512);                     // zero site (256B used)

    // stats (5376 B) + zrow (512 B) contiguous -> zero 1472 floats
    zerof<<<6, 256, 0, stream>>>(stats, 1472);

    long nx = (long)N0 * 256;
    cvt16<<<(int)((nx + 255) / 256), 256, 0, stream>>>(x, xh, nx);
    wtrans16<<<(27 * 256 * 128 + 255) / 256, 256, 0, stream>>>(w_s1, w1, 256, 128);
    wtrans16<<<(27 * 128 * 128 + 255) / 256, 256, 0, stream>>>(w11, wa1, 128, 128);
    wtrans16<<<(27 * 128 * 128 + 255) / 256, 256, 0, stream>>>(w12, wa2, 128, 128);
    wtrans16<<<(27 * 128 * 128 + 255) / 256, 256, 0, stream>>>(w21, wb1, 128, 128);
    wtrans16<<<(27 * 128 * 128 + 255) / 256, 256, 0, stream>>>(w22, wb2, 128, 128);
    wtrans16<<<(27 * 128 * 32 + 255) / 256, 256, 0, stream>>>(w_s2, w2, 128, 32);

    const float inv1 = 1.f / (float)M1, inv2 = 1.f / (float)M2;
    const int g1 = 3 * 144 * 2;         // 864 blocks (64 rows x 64-col half)
    const int g2 = 5 * 144;             // 720 blocks (64 rows x 32 cols)
    const int lds01 = 27648 + 2 * 64 * 256;   // 60416 -> 2 blocks/CU
    const int lds2  = 27648 + 2 * 32 * 256;   // 44032 -> 3 blocks/CU
    const long n4a = (long)M1 * 128 / 4;
    const long n4b = (long)M2 * 32 / 4;
    const int ga = (int)((n4a + 255) / 256);
    const int gb = (int)((n4b + 255) / 256);

    // L1: spconv1 (256 -> 128)
    conv_dense<0><<<g1, 256, lds01, stream>>>(xh, w1, zrow, cbuf, stats);
    bn_apply4<<<ga, 256, 0, stream>>>((float4*)cbuf, stats, g_s1, b_s1,
                                      nullptr, fA, nullptr, n4a, 128, inv1);
    // Block 1
    conv_dense<1><<<g1, 256, lds01, stream>>>(fA, wa1, zrow, cbuf, stats + 256);
    bn_apply4<<<ga, 256, 0, stream>>>((float4*)cbuf, stats + 256, g11, b11,
                                      nullptr, fB, nullptr, n4a, 128, inv1);
    conv_dense<1><<<g1, 256, lds01, stream>>>(fB, wa2, zrow, cbuf, stats + 512);
    bn_apply4<<<ga, 256, 0, stream>>>((float4*)cbuf, stats + 512, g12, b12,
                                      (const f16x4*)fA, fA, nullptr, n4a, 128, inv1);
    // Block 2
    conv_dense<1><<<g1, 256, lds01, stream>>>(fA, wb1, zrow, cbuf, stats + 768);
    bn_apply4<<<ga, 256, 0, stream>>>((float4*)cbuf, stats + 768, g21, b21,
                                      nullptr, fB, nullptr, n4a, 128, inv1);
    conv_dense<1><<<g1, 256, lds01, stream>>>(fB, wb2, zrow, cbuf, stats + 1024);
    bn_apply4<<<ga, 256, 0, stream>>>((float4*)cbuf, stats + 1024, g22, b22,
                                      (const f16x4*)fA, fA, nullptr, n4a, 128, inv1);
    // L6: spconv2 (128 -> 32), final fp32 output
    conv_dense<2><<<g2, 256, lds2, stream>>>(fA, w2, zrow, cbuf, stats + 1280);
    bn_apply4<<<gb, 256, 0, stream>>>((float4*)cbuf, stats + 1280, g_s2, b_s2,
                                      nullptr, nullptr, (float4*)d_out, n4b, 32, inv2);
}

// Round 7
// 496.726 us; speedup vs baseline: 1.0478x; 1.0478x over previous
//
#include <hip/hip_runtime.h>
#include <stdint.h>

typedef _Float16 f16;
typedef _Float16 f16x8 __attribute__((ext_vector_type(8)));
typedef _Float16 f16x4 __attribute__((ext_vector_type(4)));
typedef float f32x4 __attribute__((ext_vector_type(4)));

#define GAS __attribute__((address_space(1)))
#define LAS __attribute__((address_space(3)))

// async global->LDS, 16 B per lane; LDS dest = wave-uniform base + lane*16
__device__ __forceinline__ void gl_lds16(const void* g, void* l) {
    __builtin_amdgcn_global_load_lds((const GAS uint32_t*)g, (LAS uint32_t*)l, 16, 0, 0);
}

__global__ __launch_bounds__(256) void zerof(float* __restrict__ p, int n) {
    int i = blockIdx.x * 256 + threadIdx.x;
    if (i < n) p[i] = 0.f;
}

__global__ __launch_bounds__(256) void cvt16(const float* __restrict__ in,
                                             f16* __restrict__ o, long n) {
    long i = (long)blockIdx.x * 256 + threadIdx.x;
    if (i < n) o[i] = (f16)in[i];
}

// Pack w [27][Cin][Cout] fp32 into MFMA B-fragment order:
// wp unit i = ((ktap*NCT + ct)*4 + kk)*64 + lane  (16 B units, 8 f16 each)
// lane's fragment: col = ct*16 + (lane&15), channels ci = h*128 + kk*32 + (lane>>4)*8 + j
// ktap = k*KH + h. A wave's B-frag load = ONE coalesced 1 KB global_load_dwordx4.
__global__ __launch_bounds__(256) void packB(const float* __restrict__ w,
                                             f16* __restrict__ wp,
                                             int Cin, int Cout, int KH) {
    const int NCT = Cout / 16;
    const long total = 27L * KH * NCT * 4 * 64;
    long i = (long)blockIdx.x * 256 + threadIdx.x;
    if (i >= total) return;
    int lane = (int)(i & 63);
    int kk   = (int)((i >> 6) & 3);
    long r   = i >> 8;
    int ct   = (int)(r % NCT);
    long kt  = r / NCT;
    int k    = (int)(kt / KH);
    int h    = (int)(kt % KH);
    int ci0  = h * 128 + kk * 32 + (lane >> 4) * 8;
    int co   = ct * 16 + (lane & 15);
    f16x8 v;
#pragma unroll
    for (int j = 0; j < 8; j++)
        v[j] = (f16)w[((long)k * Cin + ci0 + j) * Cout + co];
    ((f16x8*)wp)[i] = v;
}

// Dense implicit 3x3x3 conv, barrier-free tap loop:
//  - A: 6y x 18x halo slab (128ch fp16 = 27648 B) in LDS, DOUBLE-buffered across
//    z-stages -> only ~S (<=3) barriers per block, none inside the 9-tap loop.
//  - B: register-prefetched one tap ahead from fragment-packed wp (coalesced 1KB
//    loads; compiler emits fine-grained vmcnt(N), never a vmcnt(0) drain).
//  Block tile: 64 rows (4y x 16x) x 64 cols (col-split for COUT=128).
//  LDS 55296 B -> 2 blocks/CU, 8 waves/CU.
// LAYER 0: CIN=256 (KH=2: 2 ch-half stages, 1 z-plane, dz=1-p), COUT=128
// LAYER 1: CIN=128, planes j=p+dz,   COUT=128
// LAYER 2: CIN=128, planes j=p+dz-1, COUT=32
template <int LAYER>
__global__ __launch_bounds__(256, 2) void conv_dense(
    const f16* __restrict__ fin, const f16* __restrict__ wp,
    const f16* __restrict__ zrow, float* __restrict__ out,
    float* __restrict__ stats) {
    constexpr int COUT = (LAYER == 2) ? 32 : 128;
    constexpr int CS   = (LAYER == 2) ? 1 : 2;       // col-split factor
    constexpr int NCT  = COUT / 16;                  // global col tiles
    constexpr int KH   = (LAYER == 0) ? 2 : 1;       // channel halves per tap
    constexpr int INRB = (LAYER == 0) ? 512 : 256;   // input row bytes
    constexpr int RT   = (LAYER == 2) ? 1 : 2;       // 16-row tiles per wave
    constexpr int CT   = 2;                          // 16-col tiles per wave
    __shared__ char ldsA0[27648];
    __shared__ char ldsA1[27648];

    const int b = blockIdx.x;
    int p, t0, chh;
    if (CS == 2) { p = b / 288; int r = b % 288; t0 = r >> 1; chh = r & 1; }
    else         { p = b / 144; t0 = b % 144; chh = 0; }
    const int y0 = (t0 / 6) * 4;
    const int x0 = (t0 % 6) * 16;
    const int tid = threadIdx.x;
    const int lane = tid & 63;
    const int wave = tid >> 6;
    const int q = lane >> 4;
    const int r16 = lane & 15;
    const int wry = (LAYER == 2) ? wave : (wave >> 1) * 2;           // y base (rows of 16)
    const int ctbase = (LAYER == 2) ? 0 : chh * 4 + (wave & 1) * 2;  // global col tile

    // stage list (block-uniform): z-planes (ch-halves for LAYER 0)
    int S = 0;
    int js[3], dzs[3], hs[3];
    if (LAYER == 0) {
        js[0] = 0; dzs[0] = 1 - p; hs[0] = 0;
        js[1] = 0; dzs[1] = 1 - p; hs[1] = 1;
        S = 2;
    } else if (LAYER == 1) {
        for (int dz = -1; dz <= 1; dz++) {
            int j = p + dz;
            if (0 <= j && j < 3) { js[S] = j; dzs[S] = dz; hs[S] = 0; S++; }
        }
    } else {
        for (int dz = -1; dz <= 1; dz++) {
            int j = p + dz - 1;
            if (0 <= j && j < 3) { js[S] = j; dzs[S] = dz; hs[S] = 0; S++; }
        }
    }

    auto stageA = [&](int s, char* buf) {
        const int j = js[s], h = hs[s];
        const long pbase = (long)j * 9216;
        for (int ch = wave; ch < 27; ch += 4) {
            int site = ch * 4 + q;
            int sy = site / 18;
            int sx = site - sy * 18;
            int y = y0 - 1 + sy;
            int x = x0 - 1 + sx;
            int cc = r16 ^ (site & 7);
            bool ok = ((unsigned)y < 96u) & ((unsigned)x < 96u);
            const char* src = ok
                ? (const char*)fin + (pbase + y * 96 + x) * INRB + h * 256 + cc * 16
                : (const char*)zrow + cc * 16;
            gl_lds16(src, buf + ch * 1024);
        }
    };

    const f16x8* wpv = (const f16x8*)wp;
    f16x8 B0[CT][4], B1[CT][4];
    auto loadB = [&](f16x8 (&B)[CT][4], int ktap) {
        const long base = (long)ktap * NCT * 4 * 64 + lane;
#pragma unroll
        for (int c = 0; c < CT; c++)
#pragma unroll
            for (int kk = 0; kk < 4; kk++)
                B[c][kk] = wpv[base + ((ctbase + c) * 4 + kk) * 64];
    };

    f32x4 acc[RT][CT];
#pragma unroll
    for (int tr = 0; tr < RT; tr++)
#pragma unroll
        for (int c = 0; c < CT; c++) acc[tr][c] = f32x4{0.f, 0.f, 0.f, 0.f};

    auto compute = [&](int dy, int dx, const char* bufA, f16x8 (&B)[CT][4]) {
#pragma unroll
        for (int kk = 0; kk < 4; kk++) {
            const int c16 = kk * 4 + q;
            f16x8 Af[RT];
#pragma unroll
            for (int tr = 0; tr < RT; tr++) {
                int site = (wry + tr + 1 + dy) * 18 + 1 + dx + r16;
                Af[tr] = *(const f16x8*)(bufA + site * 256 + ((c16 ^ (site & 7)) << 4));
            }
#pragma unroll
            for (int tr = 0; tr < RT; tr++)
#pragma unroll
                for (int c = 0; c < CT; c++)
                    acc[tr][c] = __builtin_amdgcn_mfma_f32_16x16x32_f16(
                        Af[tr], B[c][kk], acc[tr][c], 0, 0, 0);
        }
    };

    stageA(0, ldsA0);
    loadB(B0, ((dzs[0] + 1) * 9) * KH + hs[0]);
    __syncthreads();   // drains stageA(0) + B0 (once per block)

    for (int s = 0; s < S; s++) {
        const char* bufA = (s & 1) ? ldsA1 : ldsA0;
        const int k9 = (dzs[s] + 1) * 9;
        const int hc = hs[s];
#pragma unroll
        for (int i = 0; i < 9; i++) {
            if (i < 8) {
                int kt = (k9 + i + 1) * KH + hc;
                if ((i & 1) == 0) loadB(B1, kt); else loadB(B0, kt);
            }
            if (i == 0 && s + 1 < S) stageA(s + 1, ((s + 1) & 1) ? ldsA1 : ldsA0);
            if ((i & 1) == 0) compute(i / 3 - 1, i % 3 - 1, bufA, B0);
            else              compute(i / 3 - 1, i % 3 - 1, bufA, B1);
        }
        if (s + 1 < S) {
            loadB(B0, ((dzs[s + 1] + 1) * 9) * KH + hs[s + 1]);
            __syncthreads();   // stage boundary: A(s+1) slab ready, readers done
        }
    }
    // Epilogue: D row = q*4+reg within a 16-site (x) tile; write + fused BN stats.
#pragma unroll
    for (int c = 0; c < CT; c++) {
        const int col = (ctbase + c) * 16 + r16;
        float sum = 0.f, ssq = 0.f;
#pragma unroll
        for (int tr = 0; tr < RT; tr++) {
            const int ly = wry + tr;
#pragma unroll
            for (int r = 0; r < 4; r++) {
                const int lx = q * 4 + r;
                float v = acc[tr][c][r];
                out[((long)p * 9216 + (long)(y0 + ly) * 96 + x0 + lx) * COUT + col] = v;
                sum += v;
                ssq = fmaf(v, v, ssq);
            }
        }
        sum += __shfl_xor(sum, 16);
        sum += __shfl_xor(sum, 32);
        ssq += __shfl_xor(ssq, 16);
        ssq += __shfl_xor(ssq, 32);
        if (q == 0) {
            atomicAdd(&stats[col], sum);
            atomicAdd(&stats[COUT + col], ssq);
        }
    }
}

// BN(train) + optional residual + ReLU, 4 elems/thread.
__global__ __launch_bounds__(256) void bn_apply4(
    const float4* __restrict__ f, const float* __restrict__ sums,
    const float* __restrict__ g, const float* __restrict__ bta,
    const f16x4* __restrict__ idn, f16* __restrict__ outh,
    float4* __restrict__ outf, long n4, int C, float invM) {
    long i = (long)blockIdx.x * 256 + threadIdx.x;
    if (i >= n4) return;
    int col0 = (int)((i * 4) & (C - 1));
    float4 v = f[i];
    float r[4] = {v.x, v.y, v.z, v.w};
    f16x4 id = {};
    if (idn) id = idn[i];
    f16x4 ho;
#pragma unroll
    for (int j = 0; j < 4; j++) {
        int c = col0 + j;
        float mu = sums[c] * invM;
        float var = sums[C + c] * invM - mu * mu;
        var = fmaxf(var, 0.f);
        float sc = g[c] * rsqrtf(var + 1e-5f);
        float x = (r[j] - mu) * sc + bta[c];
        if (idn) x += (float)id[j];
        x = fmaxf(x, 0.f);
        r[j] = x;
        ho[j] = (f16)x;
    }
    if (outf) outf[i] = make_float4(r[0], r[1], r[2], r[3]);
    else *(f16x4*)(outh + i * 4) = ho;
}

extern "C" void kernel_launch(void* const* d_in, const int* in_sizes, int n_in,
                              void* d_out, int out_size, void* d_ws, size_t ws_size,
                              hipStream_t stream) {
    (void)n_in; (void)out_size; (void)ws_size;
    const float* x    = (const float*)d_in[0];
    const float* w_s1 = (const float*)d_in[1];
    const float* g_s1 = (const float*)d_in[2];
    const float* b_s1 = (const float*)d_in[3];
    const float* w11  = (const float*)d_in[4];
    const float* g11  = (const float*)d_in[5];
    const float* b11  = (const float*)d_in[6];
    const float* w12  = (const float*)d_in[7];
    const float* g12  = (const float*)d_in[8];
    const float* b12  = (const float*)d_in[9];
    const float* w21  = (const float*)d_in[10];
    const float* g21  = (const float*)d_in[11];
    const float* b21  = (const float*)d_in[12];
    const float* w22  = (const float*)d_in[13];
    const float* g22  = (const float*)d_in[14];
    const float* b22  = (const float*)d_in[15];
    const float* w_s2 = (const float*)d_in[16];
    const float* g_s2 = (const float*)d_in[17];
    const float* b_s2 = (const float*)d_in[18];

    const int N0 = in_sizes[0] / 256;   // 9216
    const int M1 = in_sizes[19] / 27;   // 27648
    const int M2 = in_sizes[21] / 27;   // 46080

    char* base = (char*)d_ws;
    size_t off = 0;
    auto alloc = [&](size_t bytes) -> char* {
        off = (off + 255) & ~(size_t)255;
        char* p = base + off;
        off += bytes;
        return p;
    };
    f16* xh  = (f16*)alloc((size_t)N0 * 256 * 2);
    f16* w1  = (f16*)alloc(27UL * 2 * 8 * 4 * 64 * 16);   // L0 pack (KH=2)
    f16* wa1 = (f16*)alloc(27UL * 8 * 4 * 64 * 16);
    f16* wa2 = (f16*)alloc(27UL * 8 * 4 * 64 * 16);
    f16* wb1 = (f16*)alloc(27UL * 8 * 4 * 64 * 16);
    f16* wb2 = (f16*)alloc(27UL * 8 * 4 * 64 * 16);
    f16* w2  = (f16*)alloc(27UL * 2 * 4 * 64 * 16);       // L2 pack (NCT=2)
    f16* fA  = (f16*)alloc((size_t)M1 * 128 * 2);
    f16* fB  = (f16*)alloc((size_t)M1 * 128 * 2);
    float* cbuf  = (float*)alloc((size_t)M1 * 128 * 4);   // covers M2*32 too
    float* stats = (float*)alloc(1344UL * 4);             // 5x256 + 64
    f16*   zrow  = (f16*)alloc(512);                      // zero site (256B used)

    // stats (5376 B) + zrow (512 B) contiguous -> zero 1472 floats
    zerof<<<6, 256, 0, stream>>>(stats, 1472);

    long nx = (long)N0 * 256;
    cvt16<<<(int)((nx + 255) / 256), 256, 0, stream>>>(x, xh, nx);
    packB<<<(27 * 2 * 8 * 4 * 64 + 255) / 256, 256, 0, stream>>>(w_s1, w1, 256, 128, 2);
    packB<<<(27 * 8 * 4 * 64 + 255) / 256, 256, 0, stream>>>(w11, wa1, 128, 128, 1);
    packB<<<(27 * 8 * 4 * 64 + 255) / 256, 256, 0, stream>>>(w12, wa2, 128, 128, 1);
    packB<<<(27 * 8 * 4 * 64 + 255) / 256, 256, 0, stream>>>(w21, wb1, 128, 128, 1);
    packB<<<(27 * 8 * 4 * 64 + 255) / 256, 256, 0, stream>>>(w22, wb2, 128, 128, 1);
    packB<<<(27 * 2 * 4 * 64 + 255) / 256, 256, 0, stream>>>(w_s2, w2, 128, 32, 1);

    const float inv1 = 1.f / (float)M1, inv2 = 1.f / (float)M2;
    const int g1 = 3 * 144 * 2;         // 864 blocks (64 rows x 64-col half)
    const int g2 = 5 * 144;             // 720 blocks (64 rows x 32 cols)
    const long n4a = (long)M1 * 128 / 4;
    const long n4b = (long)M2 * 32 / 4;
    const int ga = (int)((n4a + 255) / 256);
    const int gb = (int)((n4b + 255) / 256);

    // L1: spconv1 (256 -> 128)
    conv_dense<0><<<g1, 256, 0, stream>>>(xh, w1, zrow, cbuf, stats);
    bn_apply4<<<ga, 256, 0, stream>>>((float4*)cbuf, stats, g_s1, b_s1,
                                      nullptr, fA, nullptr, n4a, 128, inv1);
    // Block 1
    conv_dense<1><<<g1, 256, 0, stream>>>(fA, wa1, zrow, cbuf, stats + 256);
    bn_apply4<<<ga, 256, 0, stream>>>((float4*)cbuf, stats + 256, g11, b11,
                                      nullptr, fB, nullptr, n4a, 128, inv1);
    conv_dense<1><<<g1, 256, 0, stream>>>(fB, wa2, zrow, cbuf, stats + 512);
    bn_apply4<<<ga, 256, 0, stream>>>((float4*)cbuf, stats + 512, g12, b12,
                                      (const f16x4*)fA, fA, nullptr, n4a, 128, inv1);
    // Block 2
    conv_dense<1><<<g1, 256, 0, stream>>>(fA, wb1, zrow, cbuf, stats + 768);
    bn_apply4<<<ga, 256, 0, stream>>>((float4*)cbuf, stats + 768, g21, b21,
                                      nullptr, fB, nullptr, n4a, 128, inv1);
    conv_dense<1><<<g1, 256, 0, stream>>>(fB, wb2, zrow, cbuf, stats + 1024);
    bn_apply4<<<ga, 256, 0, stream>>>((float4*)cbuf, stats + 1024, g22, b22,
                                      (const f16x4*)fA, fA, nullptr, n4a, 128, inv1);
    // L6: spconv2 (128 -> 32), final fp32 output
    conv_dense<2><<<g2, 256, 0, stream>>>(fA, w2, zrow, cbuf, stats + 1280);
    bn_apply4<<<gb, 256, 0, stream>>>((float4*)cbuf, stats + 1280, g_s2, b_s2,
                                      nullptr, nullptr, (float4*)d_out, n4b, 32, inv2);
}